// Round 17
// baseline (280.910 us; speedup 1.0000x reference)
//
#include <hip/hip_runtime.h>
#include <stdint.h>

typedef __bf16 bf16;
typedef __bf16 bf16x8 __attribute__((ext_vector_type(8)));
typedef float f32x4 __attribute__((ext_vector_type(4)));

#define SEQ 2048
#define NHEAD 16
#define HDIM 64
#define DMODEL 1024
#define NBATCH 4
// 0.125 * log2(e): softmax runs in exp2 domain
#define ATT_SCALE 0.18033688011112042f
#define SEQHD (SEQ * HDIM)          // 131072
#define BHSTRIDE (2 * SEQHD)        // per-(b,h): K tile then V^T tile

// LDS slot invariant: L[row*64 + ((blk ^ (row&7))*8) + off] = SRC[row][blk*8+off]

__device__ __forceinline__ void gload_lds16(const bf16* g, bf16* l) {
  __builtin_amdgcn_global_load_lds(
      (const __attribute__((address_space(1))) uint32_t*)g,
      (__attribute__((address_space(3))) uint32_t*)l, 16, 0, 0);
}

__device__ __forceinline__ uint32_t pk2(float a, float b) {
  bf16 x = (bf16)a, y = (bf16)b;
  return (uint32_t)__builtin_bit_cast(uint16_t, x) |
         ((uint32_t)__builtin_bit_cast(uint16_t, y) << 16);
}

// ---- fp32 -> bf16 conversion (memory-bound pre-pass), 16 elems/thread ----
__global__ __launch_bounds__(256) void cvt_kernel(const float* __restrict__ src,
                                                  bf16* __restrict__ dst) {
  size_t i = ((size_t)blockIdx.x * 256 + threadIdx.x) * 16;
#pragma unroll
  for (int j = 0; j < 2; ++j) {
    float4 f0 = *(const float4*)(src + i + j * 8);
    float4 f1 = *(const float4*)(src + i + j * 8 + 4);
    bf16x8 v;
    v[0] = (bf16)f0.x; v[1] = (bf16)f0.y; v[2] = (bf16)f0.z; v[3] = (bf16)f0.w;
    v[4] = (bf16)f1.x; v[5] = (bf16)f1.y; v[6] = (bf16)f1.z; v[7] = (bf16)f1.w;
    *(bf16x8*)(dst + i + j * 8) = v;
  }
}

// ---- merged prep: blocks 0..767 convert Wq/Wk/Wv -> Wbf3; blocks 768..771
//      run the mask scan (posv in place, idempotent) + emit inv[b][pos]=s.
//      MUST run after cvt_x (Wbf3 and inv live in the then-dead fp32 x region). ----
__global__ __launch_bounds__(256) void prep_kernel(
    const float* __restrict__ Wq, const float* __restrict__ Wk,
    const float* __restrict__ Wv, bf16* __restrict__ Wbf3,
    int* __restrict__ posv, int* __restrict__ inv) {
  __shared__ int sums[256];
  const int bx = blockIdx.x, t = threadIdx.x;
  if (bx < 768) {
    const float* s = bx < 256 ? Wq : (bx < 512 ? Wk : Wv);
    bf16* d = Wbf3 + (size_t)(bx >> 8) * DMODEL * DMODEL;
    size_t i = ((size_t)(bx & 255) * 256 + t) * 16;
#pragma unroll
    for (int j = 0; j < 2; ++j) {
      float4 f0 = *(const float4*)(s + i + j * 8);
      float4 f1 = *(const float4*)(s + i + j * 8 + 4);
      bf16x8 v;
      v[0] = (bf16)f0.x; v[1] = (bf16)f0.y; v[2] = (bf16)f0.z; v[3] = (bf16)f0.w;
      v[4] = (bf16)f1.x; v[5] = (bf16)f1.y; v[6] = (bf16)f1.z; v[7] = (bf16)f1.w;
      *(bf16x8*)(d + i + j * 8) = v;
    }
    return;
  }
  const int b = bx - 768;
  int* m = posv + b * SEQ;
  int* iv = inv + b * SEQ;
  int f[8], cnt = 0;
#pragma unroll
  for (int j = 0; j < 8; ++j) {
    int x = m[t * 8 + j];
    int unm = (x < 0) ? 0 : ((x & 0x40000000) ? 1 : (x == 0 ? 1 : 0));
    f[j] = unm; cnt += unm;
    iv[t * 8 + j] = 0;                       // memset inv (scatter after barrier)
  }
  sums[t] = cnt;
  __syncthreads();
  if (t == 0) {
    int acc = 0;
#pragma unroll 8
    for (int i = 0; i < 256; ++i) { int s = sums[i]; sums[i] = acc; acc += s; }
  }
  __syncthreads();
  int p = sums[t];
#pragma unroll
  for (int j = 0; j < 8; ++j) {
    m[t * 8 + j] = (int)((f[j] ? 0x40000000u : 0x80000000u) | (unsigned)p);
    if (f[j]) iv[p] = t * 8 + j;
    p += f[j];
  }
}

// ---- mega launch: qproj(all 4 batches) + kvproj(chunk 0) + cvt of Wo.
//      blocks [0,1024): qproj; [1024,2048): kvproj chunk0; [2048,2304): Wo cvt.
//      Single-buffered k-loop (R14 lesson: dbuf's 48KB LDS halves blocks/CU
//      6->3 and raises HBM re-fetch — net regression. 24KB keeps 6/CU). ----
__global__ __launch_bounds__(256) void mega_kernel(
    const bf16* __restrict__ xb, const bf16* __restrict__ Wall,
    const float* __restrict__ bq, const float* __restrict__ bk,
    const float* __restrict__ bv, const int* __restrict__ posv,
    const int* __restrict__ inv, bf16* __restrict__ Qall,
    bf16* __restrict__ kv, const float* __restrict__ Wo,
    bf16* __restrict__ Wobf) {
  __shared__ __align__(16) bf16 lW[64 * 64];
  __shared__ __align__(16) bf16 lXw[4][32 * 64];
  const int bx = blockIdx.x;
  const int t = threadIdx.x, wave = t >> 6, lane = t & 63;
  const int quad = lane >> 4, c = lane & 15;
  const int sr = lane >> 3, sg = lane & 7;
  const int swzc = (sg ^ sr) * 8;

  if (bx >= 2048) {                          // ---- Wo fp32 -> bf16 ----
    size_t i = ((size_t)(bx - 2048) * 256 + t) * 16;
#pragma unroll
    for (int j = 0; j < 2; ++j) {
      float4 f0 = *(const float4*)(Wo + i + j * 8);
      float4 f1 = *(const float4*)(Wo + i + j * 8 + 4);
      bf16x8 v;
      v[0] = (bf16)f0.x; v[1] = (bf16)f0.y; v[2] = (bf16)f0.z; v[3] = (bf16)f0.w;
      v[4] = (bf16)f1.x; v[5] = (bf16)f1.y; v[6] = (bf16)f1.z; v[7] = (bf16)f1.w;
      *(bf16x8*)(Wobf + i + j * 8) = v;
    }
    return;
  }

  if (bx < 1024) {                           // ---- qproj ----
    const int m0 = (bx & 63) * 128;          // token rows 0..8191
    const int h = bx >> 6;
    const bf16* W = Wall + (size_t)(h * HDIM) * DMODEL;
    bf16* pw = lXw[wave];
    const bf16* aS = xb + (size_t)(m0 + wave * 32 + sr) * DMODEL + swzc;
    const bf16* wS = W + (size_t)(wave * 8 + sr) * DMODEL + swzc;
    f32x4 acc[2][4] = {};
    for (int k0 = 0; k0 < DMODEL; k0 += 64) {
      __syncthreads();
      gload_lds16(wS + k0, lW + wave * 512);
      gload_lds16(wS + 32 * DMODEL + k0, lW + wave * 512 + 2048);
#pragma unroll
      for (int ii = 0; ii < 4; ++ii)
        gload_lds16(aS + k0 + (size_t)ii * 8 * DMODEL, pw + ii * 512);
      __syncthreads();
#pragma unroll
      for (int kk = 0; kk < 2; ++kk) {
        bf16x8 af[2], bfr[4];
#pragma unroll
        for (int mi = 0; mi < 2; ++mi) {
          int row = mi * 16 + c;
          af[mi] = *(const bf16x8*)(pw + row * 64 + (((kk * 4 + quad) ^ (row & 7)) * 8));
        }
#pragma unroll
        for (int ni = 0; ni < 4; ++ni) {
          int row = ni * 16 + c;
          bfr[ni] = *(const bf16x8*)(lW + row * 64 + (((kk * 4 + quad) ^ (row & 7)) * 8));
        }
#pragma unroll
        for (int mi = 0; mi < 2; ++mi)
#pragma unroll
          for (int ni = 0; ni < 4; ++ni)
            acc[mi][ni] = __builtin_amdgcn_mfma_f32_16x16x32_bf16(af[mi], bfr[ni], acc[mi][ni], 0, 0, 0);
      }
    }
#pragma unroll
    for (int ni = 0; ni < 4; ++ni) {
      int hd = ni * 16 + c;
      float bqv = bq[h * HDIM + hd];
#pragma unroll
      for (int mi = 0; mi < 2; ++mi)
#pragma unroll
        for (int r = 0; r < 4; ++r) {
          int tok = m0 + wave * 32 + mi * 16 + quad * 4 + r;
          int b = tok >> 11, s = tok & 2047;
          Qall[((size_t)(b * NHEAD + h) * SEQ + s) * HDIM + hd] =
              (bf16)((acc[mi][ni][r] + bqv) * ATT_SCALE);
        }
    }
    return;
  }

  // ---- kvproj chunk 0 (batches 0,1), compacted rows, inline pad zero ----
  const int idx = bx - 1024;                 // 0..1023
  const int xi = idx & 31, yi = idx >> 5;
  const int b_loc = xi >> 4, mb = xi & 15;
  const int isV = yi >> 4, h = yi & 15;
  int v2 = posv[b_loc * SEQ + SEQ - 1];
  int nk = (v2 & 0x3FFFFFFF) + (v2 >= 0 ? 1 : 0);
  const int c0 = mb * 128;                   // compacted row base
  if (c0 >= nk) return;                      // block-uniform exit (pre-barrier)
  const bf16* W = Wall + (size_t)(1 + isV) * DMODEL * DMODEL + (size_t)(h * HDIM) * DMODEL;
  const float* bias = (isV ? bv : bk) + h * HDIM;
  bf16* pw = lXw[wave];
  const bf16* wS = W + (size_t)(wave * 8 + sr) * DMODEL + swzc;
  const int* invb = inv + b_loc * SEQ;
  int grow[4];
#pragma unroll
  for (int ii = 0; ii < 4; ++ii)
    grow[ii] = invb[c0 + wave * 32 + ii * 8 + sr];   // 0 for slots >= nk
  const bf16* xbb = xb + (size_t)b_loc * SEQ * DMODEL + swzc;
  f32x4 acc[2][4] = {};
  for (int k0 = 0; k0 < DMODEL; k0 += 64) {
    __syncthreads();
    gload_lds16(wS + k0, lW + wave * 512);
    gload_lds16(wS + 32 * DMODEL + k0, lW + wave * 512 + 2048);
#pragma unroll
    for (int ii = 0; ii < 4; ++ii)
      gload_lds16(xbb + (size_t)grow[ii] * DMODEL + k0, pw + ii * 512);
    __syncthreads();
#pragma unroll
    for (int kk = 0; kk < 2; ++kk) {
      bf16x8 af[2], bfr[4];
#pragma unroll
      for (int mi = 0; mi < 2; ++mi) {
        int row = mi * 16 + c;
        af[mi] = *(const bf16x8*)(pw + row * 64 + (((kk * 4 + quad) ^ (row & 7)) * 8));
      }
#pragma unroll
      for (int ni = 0; ni < 4; ++ni) {
        int row = ni * 16 + c;
        bfr[ni] = *(const bf16x8*)(lW + row * 64 + (((kk * 4 + quad) ^ (row & 7)) * 8));
      }
#pragma unroll
      for (int mi = 0; mi < 2; ++mi)
#pragma unroll
        for (int ni = 0; ni < 4; ++ni)
          acc[mi][ni] = __builtin_amdgcn_mfma_f32_16x16x32_bf16(af[mi], bfr[ni], acc[mi][ni], 0, 0, 0);
    }
  }
  bf16* base = kv + (size_t)(b_loc * NHEAD + h) * BHSTRIDE;
#pragma unroll
  for (int ni = 0; ni < 4; ++ni) {
    int hd = ni * 16 + c;
    float bv_ = bias[hd];
#pragma unroll
    for (int mi = 0; mi < 2; ++mi)
#pragma unroll
      for (int r = 0; r < 4; ++r) {
        int dst = c0 + wave * 32 + mi * 16 + quad * 4 + r;
        float val = (dst < nk) ? (acc[mi][ni][r] + bv_) : 0.0f;  // inline pad zero
        if (isV) base[SEQHD + (size_t)hd * SEQ + dst] = (bf16)val;
        else     base[(size_t)dst * HDIM + hd] = (bf16)val;
      }
  }
}

// ---- K/V projection over COMPACTED rows, 128-row tiles (chunk 1).
//      R17: 1D grid (1024) with XCD-aware decode — each XCD gets 4 heads
//      (1 MB W) x 8 mb-values/batch (~2 MB live gathered x rows) ~ 3 MB < L2
//      (old (32,32) grid put all 32 W panels = 4 MB + x on EVERY XCD).
//      Bijective: xcd(8) x slot(128) = 2b x 16mb x 2isV x 16h = 1024. ----
__global__ __launch_bounds__(256) void kvproj_kernel(
    const bf16* __restrict__ xb, const bf16* __restrict__ Wall,
    const float* __restrict__ bk, const float* __restrict__ bv,
    const int* __restrict__ posv, const int* __restrict__ inv,
    bf16* __restrict__ kv) {
  __shared__ __align__(16) bf16 lW[64 * 64];
  __shared__ __align__(16) bf16 lXw[4][32 * 64];
  const int t = threadIdx.x, wave = t >> 6, lane = t & 63;
  const int quad = lane >> 4, c = lane & 15;
  const int id = blockIdx.x;                 // 0..1023
  const int xcd = id & 7, slot = id >> 3;    // slot 0..127
  const int isV = slot >> 6;                 // 0..1
  const int rem = slot & 63;
  const int h = (xcd >> 1) * 4 + (rem >> 4);          // 4 heads per XCD
  const int b_loc = (rem >> 3) & 1;
  const int mb = (xcd & 1) * 8 + (rem & 7);           // 8 mb-values per XCD
  int v2 = posv[b_loc * SEQ + SEQ - 1];
  int nk = (v2 & 0x3FFFFFFF) + (v2 >= 0 ? 1 : 0);
  const int c0 = mb * 128;                   // compacted row base
  if (c0 >= nk) return;                      // block-uniform exit (pre-barrier)
  const bf16* W = Wall + (size_t)(1 + isV) * DMODEL * DMODEL + (size_t)(h * HDIM) * DMODEL;
  const float* bias = (isV ? bv : bk) + h * HDIM;
  bf16* pw = lXw[wave];
  const int sr = lane >> 3, sg = lane & 7;
  const int swzc = (sg ^ sr) * 8;
  const bf16* wS = W + (size_t)(wave * 8 + sr) * DMODEL + swzc;
  const int* invb = inv + b_loc * SEQ;
  int grow[4];
#pragma unroll
  for (int ii = 0; ii < 4; ++ii)
    grow[ii] = invb[c0 + wave * 32 + ii * 8 + sr];   // 0 for slots >= nk
  const bf16* xbb = xb + (size_t)b_loc * SEQ * DMODEL + swzc;
  f32x4 acc[2][4] = {};
  for (int k0 = 0; k0 < DMODEL; k0 += 64) {
    __syncthreads();
    gload_lds16(wS + k0, lW + wave * 512);
    gload_lds16(wS + 32 * DMODEL + k0, lW + wave * 512 + 2048);
#pragma unroll
    for (int ii = 0; ii < 4; ++ii)
      gload_lds16(xbb + (size_t)grow[ii] * DMODEL + k0, pw + ii * 512);
    __syncthreads();
#pragma unroll
    for (int kk = 0; kk < 2; ++kk) {
      bf16x8 af[2], bfr[4];
#pragma unroll
      for (int mi = 0; mi < 2; ++mi) {
        int row = mi * 16 + c;
        af[mi] = *(const bf16x8*)(pw + row * 64 + (((kk * 4 + quad) ^ (row & 7)) * 8));
      }
#pragma unroll
      for (int ni = 0; ni < 4; ++ni) {
        int row = ni * 16 + c;
        bfr[ni] = *(const bf16x8*)(lW + row * 64 + (((kk * 4 + quad) ^ (row & 7)) * 8));
      }
#pragma unroll
      for (int mi = 0; mi < 2; ++mi)
#pragma unroll
        for (int ni = 0; ni < 4; ++ni)
          acc[mi][ni] = __builtin_amdgcn_mfma_f32_16x16x32_bf16(af[mi], bfr[ni], acc[mi][ni], 0, 0, 0);
    }
  }
  bf16* base = kv + (size_t)(b_loc * NHEAD + h) * BHSTRIDE;
#pragma unroll
  for (int ni = 0; ni < 4; ++ni) {
    int hd = ni * 16 + c;
    float bv_ = bias[hd];
#pragma unroll
    for (int mi = 0; mi < 2; ++mi)
#pragma unroll
      for (int r = 0; r < 4; ++r) {
        int dst = c0 + wave * 32 + mi * 16 + quad * 4 + r;
        float val = (dst < nk) ? (acc[mi][ni][r] + bv_) : 0.0f;  // inline pad zero
        if (isV) base[SEQHD + (size_t)hd * SEQ + dst] = (bf16)val;
        else     base[(size_t)dst * HDIM + hd] = (bf16)val;
      }
  }
}

// ---- attention over COMPACTED keys (swapped QK^T; dbuf, 1 barrier/iter).
//      512 threads / 8 waves / 128 q-rows per block (512 blocks, R16).
//      K/V staged once per 128 q-rows; 1 K + 1 V gload per thread. ----
__global__ __launch_bounds__(512, 4) void attn4_kernel(
    const bf16* __restrict__ Qall, const bf16* __restrict__ KV,
    const int* __restrict__ posv, bf16* __restrict__ O, int chunk) {
  __shared__ __align__(16) bf16 lK[2][64 * 64];
  __shared__ __align__(16) bf16 lV[2][64 * 64];
  __shared__ __align__(16) bf16 lPw[8][16 * 64];
  const int t = threadIdx.x, wave = t >> 6, lane = t & 63;
  const int quad = lane >> 4, c = lane & 15;
  const int i = blockIdx.x;                  // 0..511
  const int xcd = i & 7, slot = i >> 3;      // slot 0..63
  const int bhl = xcd * 4 + (slot >> 4);     // 0..31, 4 bh per XCD
  const int qt = slot & 15;                  // 16 tiles of 128 q rows
  const int b_loc = bhl >> 4, h = bhl & 15;
  const int b = chunk * 2 + b_loc;
  const int q0 = qt * 128 + wave * 16;       // 16 q-rows per wave
  const bf16* Qh = Qall + (size_t)(b * NHEAD + h) * SEQHD;
  const bf16* Kb = KV + (size_t)(b_loc * NHEAD + h) * BHSTRIDE;
  const bf16* Vtb = Kb + SEQHD;
  bf16* pw = lPw[wave];

  int v2 = posv[b * SEQ + SEQ - 1];
  int nk = (v2 & 0x3FFFFFFF) + (v2 >= 0 ? 1 : 0);
  int NT = ((nk + 63) >> 6) << 6;

  const int srow = t >> 3;                              // 0..63 (all rows)
  const int sswz = (t & 7) ^ (srow & 7);
  const bf16* kSrc = Kb + (size_t)srow * HDIM + sswz * 8;
  const bf16* vSrc = Vtb + (size_t)srow * SEQ + sswz * 8;
  const int sOff = wave * 512;               // + buf*4096 (HW adds lane*16B)

  bf16x8 qf[2];
#pragma unroll
  for (int kk = 0; kk < 2; ++kk)
    qf[kk] = *(const bf16x8*)(Qh + (size_t)(q0 + c) * HDIM + kk * 32 + quad * 8);

  f32x4 oacc[4] = {};
  float mrun = -1e30f, lrun = 0.0f;          // softmax state for q-row = q0 + c

  const int pbase = c * 64 + (quad & 1) * 4;
  const int pswz = c & 7;

  // prologue: stage tile 0 into buf 0 (one K + one V load per thread)
  gload_lds16(kSrc, &lK[0][0] + sOff);
  gload_lds16(vSrc, &lV[0][0] + sOff);
  __syncthreads();

  int idx = 0;
  for (int kt = 0; kt < NT; kt += 64, idx ^= 1) {
    // stage next tile into buf^1 FIRST — whole iteration hides the latency
    if (kt + 64 < NT) {
      gload_lds16(kSrc + (size_t)(kt + 64) * HDIM, &lK[0][0] + (idx ^ 1) * 4096 + sOff);
      gload_lds16(vSrc + (kt + 64), &lV[0][0] + (idx ^ 1) * 4096 + sOff);
    }
    const bf16* lKc = &lK[0][0] + idx * 4096;
    const bf16* lVc = &lV[0][0] + idx * 4096;

    // QK^T swapped: lane holds S^T[k][q=c], 16 P-values of ONE q-row
    f32x4 sacc[4] = {};
    __builtin_amdgcn_s_setprio(1);
#pragma unroll
    for (int kk = 0; kk < 2; ++kk) {
      bf16x8 kf[4];
#pragma unroll
      for (int ni = 0; ni < 4; ++ni) {
        int row = ni * 16 + c;
        kf[ni] = *(const bf16x8*)(lKc + row * 64 + (((kk * 4 + quad) ^ (row & 7)) * 8));
      }
#pragma unroll
      for (int ni = 0; ni < 4; ++ni)
        sacc[ni] = __builtin_amdgcn_mfma_f32_16x16x32_bf16(kf[ni], qf[kk], sacc[ni], 0, 0, 0);
    }
    __builtin_amdgcn_s_setprio(0);

    // tail-index masking on lane-local k = kt + ni*16 + quad*4 + r
    if (kt + 64 > nk) {
      int base = kt + quad * 4 - nk;
#pragma unroll
      for (int ni = 0; ni < 4; ++ni)
#pragma unroll
        for (int r = 0; r < 4; ++r)
          if (base + ni * 16 + r >= 0) sacc[ni][r] = -3e38f;
    }

    // row max for q = c: tree + cross-quad xor16/xor32
    float m1 = fmaxf(fmaxf(sacc[0][0], sacc[0][1]), sacc[0][2]);
    float m2 = fmaxf(fmaxf(sacc[0][3], sacc[1][0]), sacc[1][1]);
    float m3 = fmaxf(fmaxf(sacc[1][2], sacc[1][3]), sacc[2][0]);
    float m4 = fmaxf(fmaxf(sacc[2][1], sacc[2][2]), sacc[2][3]);
    float m5 = fmaxf(fmaxf(sacc[3][0], sacc[3][1]), sacc[3][2]);
    float mx = fmaxf(fmaxf(fmaxf(m1, m2), m3), fmaxf(fmaxf(m4, m5), sacc[3][3]));
    mx = fmaxf(mx, __shfl_xor(mx, 16));
    mx = fmaxf(mx, __shfl_xor(mx, 32));

    // defer-rescale (T13, THR=8 in exp2 domain -> P bounded by 256)
    if (!__all(mx - mrun <= 8.0f)) {
      float mn = fmaxf(mrun, mx);
      float al = __builtin_amdgcn_exp2f(mrun - mn);
      mrun = mn;
      lrun *= al;
      float al4[4];
#pragma unroll
      for (int r = 0; r < 4; ++r) al4[r] = __shfl(al, quad * 4 + r);
#pragma unroll
      for (int ni = 0; ni < 4; ++ni)
#pragma unroll
        for (int r = 0; r < 4; ++r) oacc[ni][r] *= al4[r];
    }

    float rs = 0.0f;
#pragma unroll
    for (int ni = 0; ni < 4; ++ni)
#pragma unroll
      for (int r = 0; r < 4; ++r) {
        float e = __builtin_amdgcn_exp2f(sacc[ni][r] - mrun);
        sacc[ni][r] = e; rs += e;
      }
    rs += __shfl_xor(rs, 16);
    rs += __shfl_xor(rs, 32);
    lrun += rs;

    // pack P pairs, one b64 store per ni
#pragma unroll
    for (int ni = 0; ni < 4; ++ni) {
      uint2 u;
      u.x = pk2(sacc[ni][0], sacc[ni][1]);
      u.y = pk2(sacc[ni][2], sacc[ni][3]);
      int sl = pbase + (((ni * 2 + (quad >> 1)) ^ pswz) * 8);
      *(uint2*)(pw + sl) = u;
    }

    // PV from lPw (own wave) and lV[idx]
    __builtin_amdgcn_s_setprio(1);
#pragma unroll
    for (int kk = 0; kk < 2; ++kk) {
      bf16x8 pf, vfr[4];
      pf = *(const bf16x8*)(pw + c * 64 + (((kk * 4 + quad) ^ (c & 7)) * 8));
#pragma unroll
      for (int ni = 0; ni < 4; ++ni) {
        int row = ni * 16 + c;
        vfr[ni] = *(const bf16x8*)(lVc + row * 64 + (((kk * 4 + quad) ^ (row & 7)) * 8));
      }
#pragma unroll
      for (int ni = 0; ni < 4; ++ni)
        oacc[ni] = __builtin_amdgcn_mfma_f32_16x16x32_bf16(pf, vfr[ni], oacc[ni], 0, 0, 0);
    }
    __builtin_amdgcn_s_setprio(0);

    // ONE barrier: drains this iter's staging (vmcnt0) and guarantees all
    // waves finished reading buf[idx] before next iter's staging overwrites it
    __syncthreads();
  }

  // epilogue: 1/l broadcast from q=c layout to q=quad*4+r layout
  float linv = lrun > 0.0f ? 1.0f / lrun : 0.0f;
  float linv4[4];
#pragma unroll
  for (int r = 0; r < 4; ++r) linv4[r] = __shfl(linv, quad * 4 + r);
#pragma unroll
  for (int r = 0; r < 4; ++r) {
    size_t tok = (size_t)b * SEQ + q0 + quad * 4 + r;
#pragma unroll
    for (int ni = 0; ni < 4; ++ni)
      O[tok * DMODEL + h * HDIM + ni * 16 + c] = (bf16)(oacc[ni][r] * linv4[r]);
  }
}

// ---- output projection: out = O*Wo^T + bo (fp32). 128-row M-tiles. ----
__global__ __launch_bounds__(256) void outproj_kernel(
    const bf16* __restrict__ O, const bf16* __restrict__ Wob,
    const float* __restrict__ bo, float* __restrict__ out) {
  __shared__ __align__(16) bf16 lW[64 * 64];
  __shared__ __align__(16) bf16 lXw[4][32 * 64];
  const int t = threadIdx.x, wave = t >> 6, lane = t & 63;
  const int quad = lane >> 4, c = lane & 15;
  const int m0 = blockIdx.x * 128;           // token rows
  const int n0 = blockIdx.y * 64;            // output cols
  bf16* pw = lXw[wave];
  const int sr = lane >> 3, sg = lane & 7;
  const bf16* aS = O + (size_t)(m0 + wave * 32 + sr) * DMODEL + ((sg ^ sr) * 8);
  const bf16* wS = Wob + (size_t)(n0 + wave * 8 + sr) * DMODEL + ((sg ^ sr) * 8);
  f32x4 acc[2][4] = {};
  for (int k0 = 0; k0 < DMODEL; k0 += 64) {
    __syncthreads();
    gload_lds16(wS + k0, lW + wave * 512);
    gload_lds16(wS + 32 * DMODEL + k0, lW + wave * 512 + 2048);
#pragma unroll
    for (int ii = 0; ii < 4; ++ii)
      gload_lds16(aS + k0 + (size_t)ii * 8 * DMODEL, pw + ii * 512);
    __syncthreads();
#pragma unroll
    for (int kk = 0; kk < 2; ++kk) {
      bf16x8 af[2], bfr[4];
#pragma unroll
      for (int mi = 0; mi < 2; ++mi) {
        int row = mi * 16 + c;
        af[mi] = *(const bf16x8*)(pw + row * 64 + (((kk * 4 + quad) ^ (row & 7)) * 8));
      }
#pragma unroll
      for (int ni = 0; ni < 4; ++ni) {
        int row = ni * 16 + c;
        bfr[ni] = *(const bf16x8*)(lW + row * 64 + (((kk * 4 + quad) ^ (row & 7)) * 8));
      }
#pragma unroll
      for (int mi = 0; mi < 2; ++mi)
#pragma unroll
        for (int ni = 0; ni < 4; ++ni)
          acc[mi][ni] = __builtin_amdgcn_mfma_f32_16x16x32_bf16(af[mi], bfr[ni], acc[mi][ni], 0, 0, 0);
    }
  }
#pragma unroll
  for (int ni = 0; ni < 4; ++ni) {
    int gn = n0 + ni * 16 + c;
    float bv_ = bo[gn];
#pragma unroll
    for (int mi = 0; mi < 2; ++mi)
#pragma unroll
      for (int r = 0; r < 4; ++r) {
        int gm = m0 + wave * 32 + mi * 16 + quad * 4 + r;
        out[(size_t)gm * DMODEL + gn] = acc[mi][ni][r] + bv_;
      }
  }
}

extern "C" void kernel_launch(void* const* d_in, const int* in_sizes, int n_in,
                              void* d_out, int out_size, void* d_ws, size_t ws_size,
                              hipStream_t stream) {
  const float* x  = (const float*)d_in[0];
  int*         posv = (int*)d_in[1];                 // mask -> compacted pos (in place)
  const float* Wq = (const float*)d_in[2]; const float* bq = (const float*)d_in[3];
  const float* Wk = (const float*)d_in[4]; const float* bk = (const float*)d_in[5];
  const float* Wv = (const float*)d_in[6]; const float* bv = (const float*)d_in[7];
  const float* Wo = (const float*)d_in[8]; const float* bo = (const float*)d_in[9];
  float* out = (float*)d_out;
  char* outc = (char*)d_out;
  char* xc   = (char*)d_in[0];
  const size_t half = (size_t)NBATCH * SEQ * DMODEL * 2;  // 16,777,216 B
  const size_t qtr  = half / 2;                            // 8,388,608 B

  // Regions (16.78 MB each): R0=d_out.lo R1=d_out.hi R2=x.lo R3=x.hi
  //   cvt_x:   x(R2∪R3) -> xbf(R1)               [x fp32 dead after this]
  //   prep:    Wq/Wk/Wv -> Wbf3(R3.hi); scan posv in place + inv (R3.hi tail)
  //            [after cvt_x: Wbf3 and inv overlap fp32 x — R8 lesson]
  //   mega:    qproj -> Qall(R0); kvproj0 -> KV(R2); Wo -> Wobf(d_in[2], dead
  //            fp32 Wq — only prep read it)
  //   attn_A:  Qall.lo,KV -> O.lo(R3.lo)
  //   kvproj1: xbf.hi gather(inv) -> KV(R2)
  //   attn_B:  Qall.hi,KV -> O.hi(R3.hi)         [overwrites dead Wbf3+inv]
  //   outproj: O(R3),Wobf(d_in[2]) -> out(R0∪R1)
  bf16* Qall = (bf16*)d_out;
  bf16* xbf  = (bf16*)(outc + half);
  bf16* KV   = (bf16*)xc;
  bf16* O    = (bf16*)(xc + half);
  bf16* Wbf3 = (bf16*)(xc + half + qtr);
  int*  inv  = (int*)(xc + half + qtr + (size_t)3 * DMODEL * DMODEL * 2);
  bf16* Wobf = (bf16*)d_in[2];

  cvt_kernel<<<dim3(2048), 256, 0, stream>>>(x, xbf);
  prep_kernel<<<dim3(772), 256, 0, stream>>>(Wq, Wk, Wv, Wbf3, posv, inv);
  mega_kernel<<<dim3(2304), 256, 0, stream>>>(xbf, Wbf3, bq, bk, bv, posv, inv,
                                              Qall, KV, Wo, Wobf);
  attn4_kernel<<<dim3(512), 512, 0, stream>>>(Qall, KV, posv, O, 0);
  kvproj_kernel<<<dim3(1024), 256, 0, stream>>>(xbf + (size_t)2 * SEQ * DMODEL, Wbf3, bk, bv,
                                                posv + 2 * SEQ, inv + 2 * SEQ, KV);
  attn4_kernel<<<dim3(512), 512, 0, stream>>>(Qall, KV, posv, O, 1);
  outproj_kernel<<<dim3(64, 16), 256, 0, stream>>>(O, Wobf, bo, out);
}

// Round 18
// 268.317 us; speedup vs baseline: 1.0469x; 1.0469x over previous
//
#include <hip/hip_runtime.h>
#include <stdint.h>

typedef __bf16 bf16;
typedef __bf16 bf16x8 __attribute__((ext_vector_type(8)));
typedef float f32x4 __attribute__((ext_vector_type(4)));

#define SEQ 2048
#define NHEAD 16
#define HDIM 64
#define DMODEL 1024
#define NBATCH 4
// 0.125 * log2(e): softmax runs in exp2 domain
#define ATT_SCALE 0.18033688011112042f
#define SEQHD (SEQ * HDIM)          // 131072
#define BHSTRIDE (2 * SEQHD)        // per-(b,h): K tile then V^T tile

// LDS slot invariant: L[row*64 + ((blk ^ (row&7))*8) + off] = SRC[row][blk*8+off]

__device__ __forceinline__ void gload_lds16(const bf16* g, bf16* l) {
  __builtin_amdgcn_global_load_lds(
      (const __attribute__((address_space(1))) uint32_t*)g,
      (__attribute__((address_space(3))) uint32_t*)l, 16, 0, 0);
}

__device__ __forceinline__ uint32_t pk2(float a, float b) {
  bf16 x = (bf16)a, y = (bf16)b;
  return (uint32_t)__builtin_bit_cast(uint16_t, x) |
         ((uint32_t)__builtin_bit_cast(uint16_t, y) << 16);
}

// ---- fp32 -> bf16 conversion (memory-bound pre-pass), 16 elems/thread ----
__global__ __launch_bounds__(256) void cvt_kernel(const float* __restrict__ src,
                                                  bf16* __restrict__ dst) {
  size_t i = ((size_t)blockIdx.x * 256 + threadIdx.x) * 16;
#pragma unroll
  for (int j = 0; j < 2; ++j) {
    float4 f0 = *(const float4*)(src + i + j * 8);
    float4 f1 = *(const float4*)(src + i + j * 8 + 4);
    bf16x8 v;
    v[0] = (bf16)f0.x; v[1] = (bf16)f0.y; v[2] = (bf16)f0.z; v[3] = (bf16)f0.w;
    v[4] = (bf16)f1.x; v[5] = (bf16)f1.y; v[6] = (bf16)f1.z; v[7] = (bf16)f1.w;
    *(bf16x8*)(dst + i + j * 8) = v;
  }
}

// ---- merged prep: blocks 0..767 convert Wq/Wk/Wv -> Wbf3; blocks 768..771
//      run the mask scan (posv in place, idempotent) + emit inv[b][pos]=s.
//      MUST run after cvt_x (Wbf3 and inv live in the then-dead fp32 x region). ----
__global__ __launch_bounds__(256) void prep_kernel(
    const float* __restrict__ Wq, const float* __restrict__ Wk,
    const float* __restrict__ Wv, bf16* __restrict__ Wbf3,
    int* __restrict__ posv, int* __restrict__ inv) {
  __shared__ int sums[256];
  const int bx = blockIdx.x, t = threadIdx.x;
  if (bx < 768) {
    const float* s = bx < 256 ? Wq : (bx < 512 ? Wk : Wv);
    bf16* d = Wbf3 + (size_t)(bx >> 8) * DMODEL * DMODEL;
    size_t i = ((size_t)(bx & 255) * 256 + t) * 16;
#pragma unroll
    for (int j = 0; j < 2; ++j) {
      float4 f0 = *(const float4*)(s + i + j * 8);
      float4 f1 = *(const float4*)(s + i + j * 8 + 4);
      bf16x8 v;
      v[0] = (bf16)f0.x; v[1] = (bf16)f0.y; v[2] = (bf16)f0.z; v[3] = (bf16)f0.w;
      v[4] = (bf16)f1.x; v[5] = (bf16)f1.y; v[6] = (bf16)f1.z; v[7] = (bf16)f1.w;
      *(bf16x8*)(d + i + j * 8) = v;
    }
    return;
  }
  const int b = bx - 768;
  int* m = posv + b * SEQ;
  int* iv = inv + b * SEQ;
  int f[8], cnt = 0;
#pragma unroll
  for (int j = 0; j < 8; ++j) {
    int x = m[t * 8 + j];
    int unm = (x < 0) ? 0 : ((x & 0x40000000) ? 1 : (x == 0 ? 1 : 0));
    f[j] = unm; cnt += unm;
    iv[t * 8 + j] = 0;                       // memset inv (scatter after barrier)
  }
  sums[t] = cnt;
  __syncthreads();
  if (t == 0) {
    int acc = 0;
#pragma unroll 8
    for (int i = 0; i < 256; ++i) { int s = sums[i]; sums[i] = acc; acc += s; }
  }
  __syncthreads();
  int p = sums[t];
#pragma unroll
  for (int j = 0; j < 8; ++j) {
    m[t * 8 + j] = (int)((f[j] ? 0x40000000u : 0x80000000u) | (unsigned)p);
    if (f[j]) iv[p] = t * 8 + j;
    p += f[j];
  }
}

// ---- mega launch: qproj(all 4 batches) + kvproj(chunk 0) + cvt of Wo.
//      blocks [0,1024): qproj; [1024,2048): kvproj chunk0; [2048,2304): Wo cvt.
//      Single-buffered k-loop (R14 lesson: dbuf's 48KB LDS halves blocks/CU
//      6->3 and raises HBM re-fetch — net regression. 24KB keeps 6/CU). ----
__global__ __launch_bounds__(256) void mega_kernel(
    const bf16* __restrict__ xb, const bf16* __restrict__ Wall,
    const float* __restrict__ bq, const float* __restrict__ bk,
    const float* __restrict__ bv, const int* __restrict__ posv,
    const int* __restrict__ inv, bf16* __restrict__ Qall,
    bf16* __restrict__ kv, const float* __restrict__ Wo,
    bf16* __restrict__ Wobf) {
  __shared__ __align__(16) bf16 lW[64 * 64];
  __shared__ __align__(16) bf16 lXw[4][32 * 64];
  const int bx = blockIdx.x;
  const int t = threadIdx.x, wave = t >> 6, lane = t & 63;
  const int quad = lane >> 4, c = lane & 15;
  const int sr = lane >> 3, sg = lane & 7;
  const int swzc = (sg ^ sr) * 8;

  if (bx >= 2048) {                          // ---- Wo fp32 -> bf16 ----
    size_t i = ((size_t)(bx - 2048) * 256 + t) * 16;
#pragma unroll
    for (int j = 0; j < 2; ++j) {
      float4 f0 = *(const float4*)(Wo + i + j * 8);
      float4 f1 = *(const float4*)(Wo + i + j * 8 + 4);
      bf16x8 v;
      v[0] = (bf16)f0.x; v[1] = (bf16)f0.y; v[2] = (bf16)f0.z; v[3] = (bf16)f0.w;
      v[4] = (bf16)f1.x; v[5] = (bf16)f1.y; v[6] = (bf16)f1.z; v[7] = (bf16)f1.w;
      *(bf16x8*)(Wobf + i + j * 8) = v;
    }
    return;
  }

  if (bx < 1024) {                           // ---- qproj ----
    const int m0 = (bx & 63) * 128;          // token rows 0..8191
    const int h = bx >> 6;
    const bf16* W = Wall + (size_t)(h * HDIM) * DMODEL;
    bf16* pw = lXw[wave];
    const bf16* aS = xb + (size_t)(m0 + wave * 32 + sr) * DMODEL + swzc;
    const bf16* wS = W + (size_t)(wave * 8 + sr) * DMODEL + swzc;
    f32x4 acc[2][4] = {};
    for (int k0 = 0; k0 < DMODEL; k0 += 64) {
      __syncthreads();
      gload_lds16(wS + k0, lW + wave * 512);
      gload_lds16(wS + 32 * DMODEL + k0, lW + wave * 512 + 2048);
#pragma unroll
      for (int ii = 0; ii < 4; ++ii)
        gload_lds16(aS + k0 + (size_t)ii * 8 * DMODEL, pw + ii * 512);
      __syncthreads();
#pragma unroll
      for (int kk = 0; kk < 2; ++kk) {
        bf16x8 af[2], bfr[4];
#pragma unroll
        for (int mi = 0; mi < 2; ++mi) {
          int row = mi * 16 + c;
          af[mi] = *(const bf16x8*)(pw + row * 64 + (((kk * 4 + quad) ^ (row & 7)) * 8));
        }
#pragma unroll
        for (int ni = 0; ni < 4; ++ni) {
          int row = ni * 16 + c;
          bfr[ni] = *(const bf16x8*)(lW + row * 64 + (((kk * 4 + quad) ^ (row & 7)) * 8));
        }
#pragma unroll
        for (int mi = 0; mi < 2; ++mi)
#pragma unroll
          for (int ni = 0; ni < 4; ++ni)
            acc[mi][ni] = __builtin_amdgcn_mfma_f32_16x16x32_bf16(af[mi], bfr[ni], acc[mi][ni], 0, 0, 0);
      }
    }
#pragma unroll
    for (int ni = 0; ni < 4; ++ni) {
      int hd = ni * 16 + c;
      float bqv = bq[h * HDIM + hd];
#pragma unroll
      for (int mi = 0; mi < 2; ++mi)
#pragma unroll
        for (int r = 0; r < 4; ++r) {
          int tok = m0 + wave * 32 + mi * 16 + quad * 4 + r;
          int b = tok >> 11, s = tok & 2047;
          Qall[((size_t)(b * NHEAD + h) * SEQ + s) * HDIM + hd] =
              (bf16)((acc[mi][ni][r] + bqv) * ATT_SCALE);
        }
    }
    return;
  }

  // ---- kvproj chunk 0 (batches 0,1), compacted rows, inline pad zero ----
  const int idx = bx - 1024;                 // 0..1023
  const int xi = idx & 31, yi = idx >> 5;
  const int b_loc = xi >> 4, mb = xi & 15;
  const int isV = yi >> 4, h = yi & 15;
  int v2 = posv[b_loc * SEQ + SEQ - 1];
  int nk = (v2 & 0x3FFFFFFF) + (v2 >= 0 ? 1 : 0);
  const int c0 = mb * 128;                   // compacted row base
  if (c0 >= nk) return;                      // block-uniform exit (pre-barrier)
  const bf16* W = Wall + (size_t)(1 + isV) * DMODEL * DMODEL + (size_t)(h * HDIM) * DMODEL;
  const float* bias = (isV ? bv : bk) + h * HDIM;
  bf16* pw = lXw[wave];
  const bf16* wS = W + (size_t)(wave * 8 + sr) * DMODEL + swzc;
  const int* invb = inv + b_loc * SEQ;
  int grow[4];
#pragma unroll
  for (int ii = 0; ii < 4; ++ii)
    grow[ii] = invb[c0 + wave * 32 + ii * 8 + sr];   // 0 for slots >= nk
  const bf16* xbb = xb + (size_t)b_loc * SEQ * DMODEL + swzc;
  f32x4 acc[2][4] = {};
  for (int k0 = 0; k0 < DMODEL; k0 += 64) {
    __syncthreads();
    gload_lds16(wS + k0, lW + wave * 512);
    gload_lds16(wS + 32 * DMODEL + k0, lW + wave * 512 + 2048);
#pragma unroll
    for (int ii = 0; ii < 4; ++ii)
      gload_lds16(xbb + (size_t)grow[ii] * DMODEL + k0, pw + ii * 512);
    __syncthreads();
#pragma unroll
    for (int kk = 0; kk < 2; ++kk) {
      bf16x8 af[2], bfr[4];
#pragma unroll
      for (int mi = 0; mi < 2; ++mi) {
        int row = mi * 16 + c;
        af[mi] = *(const bf16x8*)(pw + row * 64 + (((kk * 4 + quad) ^ (row & 7)) * 8));
      }
#pragma unroll
      for (int ni = 0; ni < 4; ++ni) {
        int row = ni * 16 + c;
        bfr[ni] = *(const bf16x8*)(lW + row * 64 + (((kk * 4 + quad) ^ (row & 7)) * 8));
      }
#pragma unroll
      for (int mi = 0; mi < 2; ++mi)
#pragma unroll
        for (int ni = 0; ni < 4; ++ni)
          acc[mi][ni] = __builtin_amdgcn_mfma_f32_16x16x32_bf16(af[mi], bfr[ni], acc[mi][ni], 0, 0, 0);
    }
  }
  bf16* base = kv + (size_t)(b_loc * NHEAD + h) * BHSTRIDE;
#pragma unroll
  for (int ni = 0; ni < 4; ++ni) {
    int hd = ni * 16 + c;
    float bv_ = bias[hd];
#pragma unroll
    for (int mi = 0; mi < 2; ++mi)
#pragma unroll
      for (int r = 0; r < 4; ++r) {
        int dst = c0 + wave * 32 + mi * 16 + quad * 4 + r;
        float val = (dst < nk) ? (acc[mi][ni][r] + bv_) : 0.0f;  // inline pad zero
        if (isV) base[SEQHD + (size_t)hd * SEQ + dst] = (bf16)val;
        else     base[(size_t)dst * HDIM + hd] = (bf16)val;
      }
  }
}

// ---- K/V projection over COMPACTED rows, 128-row tiles (chunk 1).
//      Grid (32,32): surviving blocks (mb <= ~7) spread across all 8 XCDs
//      (R17 lesson: XCD-packing the heads starved odd XCDs after early-exit). ----
__global__ __launch_bounds__(256) void kvproj_kernel(
    const bf16* __restrict__ xb, const bf16* __restrict__ Wall,
    const float* __restrict__ bk, const float* __restrict__ bv,
    const int* __restrict__ posv, const int* __restrict__ inv,
    bf16* __restrict__ kv) {
  __shared__ __align__(16) bf16 lW[64 * 64];
  __shared__ __align__(16) bf16 lXw[4][32 * 64];
  const int t = threadIdx.x, wave = t >> 6, lane = t & 63;
  const int quad = lane >> 4, c = lane & 15;
  const int bx = blockIdx.x;
  const int b_loc = bx >> 4, mb = bx & 15;
  const int nt = blockIdx.y;
  const int isV = nt >> 4, h = nt & 15;
  int v2 = posv[b_loc * SEQ + SEQ - 1];
  int nk = (v2 & 0x3FFFFFFF) + (v2 >= 0 ? 1 : 0);
  const int c0 = mb * 128;                   // compacted row base
  if (c0 >= nk) return;                      // block-uniform exit (pre-barrier)
  const bf16* W = Wall + (size_t)(1 + isV) * DMODEL * DMODEL + (size_t)(h * HDIM) * DMODEL;
  const float* bias = (isV ? bv : bk) + h * HDIM;
  bf16* pw = lXw[wave];
  const int sr = lane >> 3, sg = lane & 7;
  const int swzc = (sg ^ sr) * 8;
  const bf16* wS = W + (size_t)(wave * 8 + sr) * DMODEL + swzc;
  const int* invb = inv + b_loc * SEQ;
  int grow[4];
#pragma unroll
  for (int ii = 0; ii < 4; ++ii)
    grow[ii] = invb[c0 + wave * 32 + ii * 8 + sr];   // 0 for slots >= nk
  const bf16* xbb = xb + (size_t)b_loc * SEQ * DMODEL + swzc;
  f32x4 acc[2][4] = {};
  for (int k0 = 0; k0 < DMODEL; k0 += 64) {
    __syncthreads();
    gload_lds16(wS + k0, lW + wave * 512);
    gload_lds16(wS + 32 * DMODEL + k0, lW + wave * 512 + 2048);
#pragma unroll
    for (int ii = 0; ii < 4; ++ii)
      gload_lds16(xbb + (size_t)grow[ii] * DMODEL + k0, pw + ii * 512);
    __syncthreads();
#pragma unroll
    for (int kk = 0; kk < 2; ++kk) {
      bf16x8 af[2], bfr[4];
#pragma unroll
      for (int mi = 0; mi < 2; ++mi) {
        int row = mi * 16 + c;
        af[mi] = *(const bf16x8*)(pw + row * 64 + (((kk * 4 + quad) ^ (row & 7)) * 8));
      }
#pragma unroll
      for (int ni = 0; ni < 4; ++ni) {
        int row = ni * 16 + c;
        bfr[ni] = *(const bf16x8*)(lW + row * 64 + (((kk * 4 + quad) ^ (row & 7)) * 8));
      }
#pragma unroll
      for (int mi = 0; mi < 2; ++mi)
#pragma unroll
        for (int ni = 0; ni < 4; ++ni)
          acc[mi][ni] = __builtin_amdgcn_mfma_f32_16x16x32_bf16(af[mi], bfr[ni], acc[mi][ni], 0, 0, 0);
    }
  }
  bf16* base = kv + (size_t)(b_loc * NHEAD + h) * BHSTRIDE;
#pragma unroll
  for (int ni = 0; ni < 4; ++ni) {
    int hd = ni * 16 + c;
    float bv_ = bias[hd];
#pragma unroll
    for (int mi = 0; mi < 2; ++mi)
#pragma unroll
      for (int r = 0; r < 4; ++r) {
        int dst = c0 + wave * 32 + mi * 16 + quad * 4 + r;
        float val = (dst < nk) ? (acc[mi][ni][r] + bv_) : 0.0f;  // inline pad zero
        if (isV) base[SEQHD + (size_t)hd * SEQ + dst] = (bf16)val;
        else     base[(size_t)dst * HDIM + hd] = (bf16)val;
      }
  }
}

// ---- attention over COMPACTED keys (swapped QK^T; dbuf, 1 barrier/iter).
//      512 threads / 8 waves / 128 q-rows per block (512 blocks, R16).
//      K/V staged once per 128 q-rows; 1 K + 1 V gload per thread. ----
__global__ __launch_bounds__(512, 4) void attn4_kernel(
    const bf16* __restrict__ Qall, const bf16* __restrict__ KV,
    const int* __restrict__ posv, bf16* __restrict__ O, int chunk) {
  __shared__ __align__(16) bf16 lK[2][64 * 64];
  __shared__ __align__(16) bf16 lV[2][64 * 64];
  __shared__ __align__(16) bf16 lPw[8][16 * 64];
  const int t = threadIdx.x, wave = t >> 6, lane = t & 63;
  const int quad = lane >> 4, c = lane & 15;
  const int i = blockIdx.x;                  // 0..511
  const int xcd = i & 7, slot = i >> 3;      // slot 0..63
  const int bhl = xcd * 4 + (slot >> 4);     // 0..31, 4 bh per XCD
  const int qt = slot & 15;                  // 16 tiles of 128 q rows
  const int b_loc = bhl >> 4, h = bhl & 15;
  const int b = chunk * 2 + b_loc;
  const int q0 = qt * 128 + wave * 16;       // 16 q-rows per wave
  const bf16* Qh = Qall + (size_t)(b * NHEAD + h) * SEQHD;
  const bf16* Kb = KV + (size_t)(b_loc * NHEAD + h) * BHSTRIDE;
  const bf16* Vtb = Kb + SEQHD;
  bf16* pw = lPw[wave];

  int v2 = posv[b * SEQ + SEQ - 1];
  int nk = (v2 & 0x3FFFFFFF) + (v2 >= 0 ? 1 : 0);
  int NT = ((nk + 63) >> 6) << 6;

  const int srow = t >> 3;                              // 0..63 (all rows)
  const int sswz = (t & 7) ^ (srow & 7);
  const bf16* kSrc = Kb + (size_t)srow * HDIM + sswz * 8;
  const bf16* vSrc = Vtb + (size_t)srow * SEQ + sswz * 8;
  const int sOff = wave * 512;               // + buf*4096 (HW adds lane*16B)

  bf16x8 qf[2];
#pragma unroll
  for (int kk = 0; kk < 2; ++kk)
    qf[kk] = *(const bf16x8*)(Qh + (size_t)(q0 + c) * HDIM + kk * 32 + quad * 8);

  f32x4 oacc[4] = {};
  float mrun = -1e30f, lrun = 0.0f;          // softmax state for q-row = q0 + c

  const int pbase = c * 64 + (quad & 1) * 4;
  const int pswz = c & 7;

  // prologue: stage tile 0 into buf 0 (one K + one V load per thread)
  gload_lds16(kSrc, &lK[0][0] + sOff);
  gload_lds16(vSrc, &lV[0][0] + sOff);
  __syncthreads();

  int idx = 0;
  for (int kt = 0; kt < NT; kt += 64, idx ^= 1) {
    // stage next tile into buf^1 FIRST — whole iteration hides the latency
    if (kt + 64 < NT) {
      gload_lds16(kSrc + (size_t)(kt + 64) * HDIM, &lK[0][0] + (idx ^ 1) * 4096 + sOff);
      gload_lds16(vSrc + (kt + 64), &lV[0][0] + (idx ^ 1) * 4096 + sOff);
    }
    const bf16* lKc = &lK[0][0] + idx * 4096;
    const bf16* lVc = &lV[0][0] + idx * 4096;

    // QK^T swapped: lane holds S^T[k][q=c], 16 P-values of ONE q-row
    f32x4 sacc[4] = {};
    __builtin_amdgcn_s_setprio(1);
#pragma unroll
    for (int kk = 0; kk < 2; ++kk) {
      bf16x8 kf[4];
#pragma unroll
      for (int ni = 0; ni < 4; ++ni) {
        int row = ni * 16 + c;
        kf[ni] = *(const bf16x8*)(lKc + row * 64 + (((kk * 4 + quad) ^ (row & 7)) * 8));
      }
#pragma unroll
      for (int ni = 0; ni < 4; ++ni)
        sacc[ni] = __builtin_amdgcn_mfma_f32_16x16x32_bf16(kf[ni], qf[kk], sacc[ni], 0, 0, 0);
    }
    __builtin_amdgcn_s_setprio(0);

    // tail-index masking on lane-local k = kt + ni*16 + quad*4 + r
    if (kt + 64 > nk) {
      int base = kt + quad * 4 - nk;
#pragma unroll
      for (int ni = 0; ni < 4; ++ni)
#pragma unroll
        for (int r = 0; r < 4; ++r)
          if (base + ni * 16 + r >= 0) sacc[ni][r] = -3e38f;
    }

    // row max for q = c: tree + cross-quad xor16/xor32
    float m1 = fmaxf(fmaxf(sacc[0][0], sacc[0][1]), sacc[0][2]);
    float m2 = fmaxf(fmaxf(sacc[0][3], sacc[1][0]), sacc[1][1]);
    float m3 = fmaxf(fmaxf(sacc[1][2], sacc[1][3]), sacc[2][0]);
    float m4 = fmaxf(fmaxf(sacc[2][1], sacc[2][2]), sacc[2][3]);
    float m5 = fmaxf(fmaxf(sacc[3][0], sacc[3][1]), sacc[3][2]);
    float mx = fmaxf(fmaxf(fmaxf(m1, m2), m3), fmaxf(fmaxf(m4, m5), sacc[3][3]));
    mx = fmaxf(mx, __shfl_xor(mx, 16));
    mx = fmaxf(mx, __shfl_xor(mx, 32));

    // defer-rescale (T13, THR=8 in exp2 domain -> P bounded by 256)
    if (!__all(mx - mrun <= 8.0f)) {
      float mn = fmaxf(mrun, mx);
      float al = __builtin_amdgcn_exp2f(mrun - mn);
      mrun = mn;
      lrun *= al;
      float al4[4];
#pragma unroll
      for (int r = 0; r < 4; ++r) al4[r] = __shfl(al, quad * 4 + r);
#pragma unroll
      for (int ni = 0; ni < 4; ++ni)
#pragma unroll
        for (int r = 0; r < 4; ++r) oacc[ni][r] *= al4[r];
    }

    float rs = 0.0f;
#pragma unroll
    for (int ni = 0; ni < 4; ++ni)
#pragma unroll
      for (int r = 0; r < 4; ++r) {
        float e = __builtin_amdgcn_exp2f(sacc[ni][r] - mrun);
        sacc[ni][r] = e; rs += e;
      }
    rs += __shfl_xor(rs, 16);
    rs += __shfl_xor(rs, 32);
    lrun += rs;

    // pack P pairs, one b64 store per ni
#pragma unroll
    for (int ni = 0; ni < 4; ++ni) {
      uint2 u;
      u.x = pk2(sacc[ni][0], sacc[ni][1]);
      u.y = pk2(sacc[ni][2], sacc[ni][3]);
      int sl = pbase + (((ni * 2 + (quad >> 1)) ^ pswz) * 8);
      *(uint2*)(pw + sl) = u;
    }

    // PV from lPw (own wave) and lV[idx]
    __builtin_amdgcn_s_setprio(1);
#pragma unroll
    for (int kk = 0; kk < 2; ++kk) {
      bf16x8 pf, vfr[4];
      pf = *(const bf16x8*)(pw + c * 64 + (((kk * 4 + quad) ^ (c & 7)) * 8));
#pragma unroll
      for (int ni = 0; ni < 4; ++ni) {
        int row = ni * 16 + c;
        vfr[ni] = *(const bf16x8*)(lVc + row * 64 + (((kk * 4 + quad) ^ (row & 7)) * 8));
      }
#pragma unroll
      for (int ni = 0; ni < 4; ++ni)
        oacc[ni] = __builtin_amdgcn_mfma_f32_16x16x32_bf16(pf, vfr[ni], oacc[ni], 0, 0, 0);
    }
    __builtin_amdgcn_s_setprio(0);

    // ONE barrier: drains this iter's staging (vmcnt0) and guarantees all
    // waves finished reading buf[idx] before next iter's staging overwrites it
    __syncthreads();
  }

  // epilogue: 1/l broadcast from q=c layout to q=quad*4+r layout
  float linv = lrun > 0.0f ? 1.0f / lrun : 0.0f;
  float linv4[4];
#pragma unroll
  for (int r = 0; r < 4; ++r) linv4[r] = __shfl(linv, quad * 4 + r);
#pragma unroll
  for (int r = 0; r < 4; ++r) {
    size_t tok = (size_t)b * SEQ + q0 + quad * 4 + r;
#pragma unroll
    for (int ni = 0; ni < 4; ++ni)
      O[tok * DMODEL + h * HDIM + ni * 16 + c] = (bf16)(oacc[ni][r] * linv4[r]);
  }
}

// ---- output projection: out = O*Wo^T + bo (fp32). 128-row M-tiles. ----
__global__ __launch_bounds__(256) void outproj_kernel(
    const bf16* __restrict__ O, const bf16* __restrict__ Wob,
    const float* __restrict__ bo, float* __restrict__ out) {
  __shared__ __align__(16) bf16 lW[64 * 64];
  __shared__ __align__(16) bf16 lXw[4][32 * 64];
  const int t = threadIdx.x, wave = t >> 6, lane = t & 63;
  const int quad = lane >> 4, c = lane & 15;
  const int m0 = blockIdx.x * 128;           // token rows
  const int n0 = blockIdx.y * 64;            // output cols
  bf16* pw = lXw[wave];
  const int sr = lane >> 3, sg = lane & 7;
  const bf16* aS = O + (size_t)(m0 + wave * 32 + sr) * DMODEL + ((sg ^ sr) * 8);
  const bf16* wS = Wob + (size_t)(n0 + wave * 8 + sr) * DMODEL + ((sg ^ sr) * 8);
  f32x4 acc[2][4] = {};
  for (int k0 = 0; k0 < DMODEL; k0 += 64) {
    __syncthreads();
    gload_lds16(wS + k0, lW + wave * 512);
    gload_lds16(wS + 32 * DMODEL + k0, lW + wave * 512 + 2048);
#pragma unroll
    for (int ii = 0; ii < 4; ++ii)
      gload_lds16(aS + k0 + (size_t)ii * 8 * DMODEL, pw + ii * 512);
    __syncthreads();
#pragma unroll
    for (int kk = 0; kk < 2; ++kk) {
      bf16x8 af[2], bfr[4];
#pragma unroll
      for (int mi = 0; mi < 2; ++mi) {
        int row = mi * 16 + c;
        af[mi] = *(const bf16x8*)(pw + row * 64 + (((kk * 4 + quad) ^ (row & 7)) * 8));
      }
#pragma unroll
      for (int ni = 0; ni < 4; ++ni) {
        int row = ni * 16 + c;
        bfr[ni] = *(const bf16x8*)(lW + row * 64 + (((kk * 4 + quad) ^ (row & 7)) * 8));
      }
#pragma unroll
      for (int mi = 0; mi < 2; ++mi)
#pragma unroll
        for (int ni = 0; ni < 4; ++ni)
          acc[mi][ni] = __builtin_amdgcn_mfma_f32_16x16x32_bf16(af[mi], bfr[ni], acc[mi][ni], 0, 0, 0);
    }
  }
#pragma unroll
  for (int ni = 0; ni < 4; ++ni) {
    int gn = n0 + ni * 16 + c;
    float bv_ = bo[gn];
#pragma unroll
    for (int mi = 0; mi < 2; ++mi)
#pragma unroll
      for (int r = 0; r < 4; ++r) {
        int gm = m0 + wave * 32 + mi * 16 + quad * 4 + r;
        out[(size_t)gm * DMODEL + gn] = acc[mi][ni][r] + bv_;
      }
  }
}

extern "C" void kernel_launch(void* const* d_in, const int* in_sizes, int n_in,
                              void* d_out, int out_size, void* d_ws, size_t ws_size,
                              hipStream_t stream) {
  const float* x  = (const float*)d_in[0];
  int*         posv = (int*)d_in[1];                 // mask -> compacted pos (in place)
  const float* Wq = (const float*)d_in[2]; const float* bq = (const float*)d_in[3];
  const float* Wk = (const float*)d_in[4]; const float* bk = (const float*)d_in[5];
  const float* Wv = (const float*)d_in[6]; const float* bv = (const float*)d_in[7];
  const float* Wo = (const float*)d_in[8]; const float* bo = (const float*)d_in[9];
  float* out = (float*)d_out;
  char* outc = (char*)d_out;
  char* xc   = (char*)d_in[0];
  const size_t half = (size_t)NBATCH * SEQ * DMODEL * 2;  // 16,777,216 B
  const size_t qtr  = half / 2;                            // 8,388,608 B

  // Regions (16.78 MB each): R0=d_out.lo R1=d_out.hi R2=x.lo R3=x.hi
  //   cvt_x:   x(R2∪R3) -> xbf(R1)               [x fp32 dead after this]
  //   prep:    Wq/Wk/Wv -> Wbf3(R3.hi); scan posv in place + inv (R3.hi tail)
  //            [after cvt_x: Wbf3 and inv overlap fp32 x — R8 lesson]
  //   mega:    qproj -> Qall(R0); kvproj0 -> KV(R2); Wo -> Wobf(d_in[2], dead
  //            fp32 Wq — only prep read it)
  //   attn_A:  Qall.lo,KV -> O.lo(R3.lo)
  //   kvproj1: xbf.hi gather(inv) -> KV(R2)
  //   attn_B:  Qall.hi,KV -> O.hi(R3.hi)         [overwrites dead Wbf3+inv]
  //   outproj: O(R3),Wobf(d_in[2]) -> out(R0∪R1)
  bf16* Qall = (bf16*)d_out;
  bf16* xbf  = (bf16*)(outc + half);
  bf16* KV   = (bf16*)xc;
  bf16* O    = (bf16*)(xc + half);
  bf16* Wbf3 = (bf16*)(xc + half + qtr);
  int*  inv  = (int*)(xc + half + qtr + (size_t)3 * DMODEL * DMODEL * 2);
  bf16* Wobf = (bf16*)d_in[2];

  cvt_kernel<<<dim3(2048), 256, 0, stream>>>(x, xbf);
  prep_kernel<<<dim3(772), 256, 0, stream>>>(Wq, Wk, Wv, Wbf3, posv, inv);
  mega_kernel<<<dim3(2304), 256, 0, stream>>>(xbf, Wbf3, bq, bk, bv, posv, inv,
                                              Qall, KV, Wo, Wobf);
  attn4_kernel<<<dim3(512), 512, 0, stream>>>(Qall, KV, posv, O, 0);
  kvproj_kernel<<<dim3(32, 32), 256, 0, stream>>>(xbf + (size_t)2 * SEQ * DMODEL, Wbf3, bk, bv,
                                                  posv + 2 * SEQ, inv + 2 * SEQ, KV);
  attn4_kernel<<<dim3(512), 512, 0, stream>>>(Qall, KV, posv, O, 1);
  outproj_kernel<<<dim3(64, 16), 256, 0, stream>>>(O, Wobf, bo, out);
}